// Round 1
// baseline (2390.875 us; speedup 1.0000x reference)
//
#include <hip/hip_runtime.h>
#include <hip/hip_bf16.h>
#include <math.h>

// GAT 2-layer inference on MI355X.
// Structure: dtype-detect -> CSR build (hist/scan/scatter) -> GEMM1+alpha ->
// agg1+ELU -> GEMM2+alpha -> agg2+log_softmax.
// All intermediates fp32 in d_ws (~89 MB needed).
// Softmax max-subtraction skipped: logits are O(+-10), exp safe in fp32,
// and the shift cancels exactly in alpha = exp(e)/sum(exp(e)).

#define DEV __device__ __forceinline__

constexpr int N_NODES = 100000;
constexpr int N_EDGES = 3200000;
constexpr int F_IN    = 500;
constexpr int HEADS   = 8;
constexpr int HID     = 8;
constexpr int D1      = HEADS * HID;   // 64
constexpr int NC      = 41;

constexpr int CHUNK  = 1024;
constexpr int NCHUNK = (N_NODES + CHUNK - 1) / CHUNK;   // 98

DEV float bf2f(unsigned short u) {
    return __uint_as_float(((unsigned int)u) << 16);
}
DEV float leaky(float e) { return e > 0.f ? e : 0.2f * e; }

// ---------------------------------------------------------------- detect + convert weights
__global__ void k_detect_convert(const void* xraw, const void* eraw,
                                 const void* w1, const void* a1s, const void* a1d,
                                 const void* w2, const void* a2s, const void* a2d,
                                 float* W1f, float* A1Sf, float* A1Df,
                                 float* W2f, float* A2Sf, float* A2Df,
                                 int* flags) {
    __shared__ int sf;
    if (threadIdx.x == 0) {
        // x: bf16 stream -> every u16 is a sane bf16; f32 stream -> even u16s
        // are low mantissa bits (uniform), rarely exponent-plausible.
        const unsigned short* xu = (const unsigned short*)xraw;
        int valid = 0;
        for (int i = 0; i < 64; i++) {
            unsigned short v = xu[2 * i];
            int e = (v >> 7) & 0xFF;
            if (e == 0 || (e >= 90 && e <= 150)) valid++;
        }
        int xf32 = (valid < 56) ? 1 : 0;
        // edge_index: int64 -> odd u32 words are all zero (values < 2^31).
        const unsigned int* eu = (const unsigned int*)eraw;
        int zeros = 0;
        for (int k = 0; k < 64; k++)
            if (eu[2 * k + 1] == 0u) zeros++;
        int e64 = (zeros == 64) ? 1 : 0;
        flags[0] = xf32;
        flags[1] = e64;
        sf = xf32;
    }
    __syncthreads();
    bool f32 = (sf != 0);
    auto conv = [&](const void* src, float* dst, int n) {
        if (f32) {
            const float* s = (const float*)src;
            for (int i = threadIdx.x; i < n; i += blockDim.x) dst[i] = s[i];
        } else {
            const unsigned short* s = (const unsigned short*)src;
            for (int i = threadIdx.x; i < n; i += blockDim.x) dst[i] = bf2f(s[i]);
        }
    };
    conv(w1, W1f, F_IN * D1);
    conv(a1s, A1Sf, HEADS * HID);
    conv(a1d, A1Df, HEADS * HID);
    conv(w2, W2f, D1 * NC);
    conv(a2s, A2Sf, NC);
    conv(a2d, A2Df, NC);
}

// ---------------------------------------------------------------- CSR build
__global__ void k_hist(const void* eraw, const int* flags, int* deg) {
    bool e64 = flags[1] != 0;
    const unsigned int* eu = (const unsigned int*)eraw;
    int i = blockIdx.x * blockDim.x + threadIdx.x;
    int stride = gridDim.x * blockDim.x;
    for (; i < N_EDGES; i += stride) {
        int dst = e64 ? (int)eu[2 * (N_EDGES + i)] : (int)eu[N_EDGES + i];
        atomicAdd(&deg[dst], 1);
    }
}

__global__ void k_scan1(const int* deg, int* bsum) {
    __shared__ int lds[256];
    int base = blockIdx.x * CHUNK + threadIdx.x * 4;
    int s = 0;
    for (int r = 0; r < 4; r++) {
        int i = base + r;
        if (i < N_NODES) s += deg[i];
    }
    lds[threadIdx.x] = s;
    __syncthreads();
    for (int o = 128; o > 0; o >>= 1) {
        if (threadIdx.x < o) lds[threadIdx.x] += lds[threadIdx.x + o];
        __syncthreads();
    }
    if (threadIdx.x == 0) bsum[blockIdx.x] = lds[0];
}

__global__ void k_scan2(int* bsum, int* off) {
    if (threadIdx.x == 0) {
        int run = 0;
        for (int c = 0; c < NCHUNK; c++) {
            int v = bsum[c];
            bsum[c] = run;
            run += v;
        }
        off[N_NODES] = run;   // == E
    }
}

__global__ void k_scan3(const int* deg, const int* bsum, int* off, int* pos) {
    __shared__ int lds[256];
    int t = threadIdx.x;
    int base = blockIdx.x * CHUNK + t * 4;
    int v[4];
    int s = 0;
    for (int r = 0; r < 4; r++) {
        int i = base + r;
        v[r] = (i < N_NODES) ? deg[i] : 0;
        s += v[r];
    }
    lds[t] = s;
    __syncthreads();
    for (int o = 1; o < 256; o <<= 1) {
        int add = (t >= o) ? lds[t - o] : 0;
        __syncthreads();
        lds[t] += add;
        __syncthreads();
    }
    int excl = bsum[blockIdx.x] + ((t > 0) ? lds[t - 1] : 0);
    for (int r = 0; r < 4; r++) {
        int i = base + r;
        if (i < N_NODES) { off[i] = excl; pos[i] = excl; }
        excl += v[r];
    }
}

__global__ void k_scatter(const void* eraw, const int* flags, int* pos, int* csr) {
    bool e64 = flags[1] != 0;
    const unsigned int* eu = (const unsigned int*)eraw;
    int i = blockIdx.x * blockDim.x + threadIdx.x;
    int stride = gridDim.x * blockDim.x;
    for (; i < N_EDGES; i += stride) {
        int src = e64 ? (int)eu[2 * i] : (int)eu[i];
        int dst = e64 ? (int)eu[2 * (N_EDGES + i)] : (int)eu[N_EDGES + i];
        int slot = atomicAdd(&pos[dst], 1);
        csr[slot] = src;
    }
}

// ---------------------------------------------------------------- GEMM1: h1 = x @ W1, + alpha halves
template <bool XF32>
DEV void gemm1_body(const void* xraw, const float* W1f,
                    const float* A1Sf, const float* A1Df,
                    float* h1, float* as1, float* ad1, int lane, int n0) {
    float acc[16];
#pragma unroll
    for (int r = 0; r < 16; r++) acc[r] = 0.f;
    const float* xf = (const float*)xraw;
    const unsigned short* xb = (const unsigned short*)xraw;
    for (int k = 0; k < F_IN; k += 4) {
        float w0 = W1f[(k + 0) * D1 + lane];
        float w1 = W1f[(k + 1) * D1 + lane];
        float w2 = W1f[(k + 2) * D1 + lane];
        float w3 = W1f[(k + 3) * D1 + lane];
#pragma unroll
        for (int r = 0; r < 16; r++) {
            size_t base = (size_t)(n0 + r) * F_IN + k;
            float x0, x1, x2, x3;
            if (XF32) {
                float4 xv = *(const float4*)(xf + base);
                x0 = xv.x; x1 = xv.y; x2 = xv.z; x3 = xv.w;
            } else {
                ushort4 xv = *(const ushort4*)(xb + base);
                x0 = bf2f(xv.x); x1 = bf2f(xv.y); x2 = bf2f(xv.z); x3 = bf2f(xv.w);
            }
            acc[r] = fmaf(x0, w0, acc[r]);
            acc[r] = fmaf(x1, w1, acc[r]);
            acc[r] = fmaf(x2, w2, acc[r]);
            acc[r] = fmaf(x3, w3, acc[r]);
        }
    }
    float a_s = A1Sf[lane], a_d = A1Df[lane];
#pragma unroll
    for (int r = 0; r < 16; r++) {
        int n = n0 + r;
        h1[(size_t)n * D1 + lane] = acc[r];
        float ts = acc[r] * a_s, td = acc[r] * a_d;
#pragma unroll
        for (int o = 1; o < 8; o <<= 1) {
            ts += __shfl_xor(ts, o, 64);
            td += __shfl_xor(td, o, 64);
        }
        if ((lane & 7) == 0) {
            as1[n * HEADS + (lane >> 3)] = ts;
            ad1[n * HEADS + (lane >> 3)] = td;
        }
    }
}

__global__ __launch_bounds__(256) void k_gemm1(const void* xraw, const int* flags,
                                               const float* W1f, const float* A1Sf,
                                               const float* A1Df, float* h1,
                                               float* as1, float* ad1) {
    int lane = threadIdx.x & 63;
    int wave = (blockIdx.x * blockDim.x + threadIdx.x) >> 6;
    int n0 = wave * 16;
    if (n0 >= N_NODES) return;
    if (flags[0])
        gemm1_body<true>(xraw, W1f, A1Sf, A1Df, h1, as1, ad1, lane, n0);
    else
        gemm1_body<false>(xraw, W1f, A1Sf, A1Df, h1, as1, ad1, lane, n0);
}

// ---------------------------------------------------------------- layer-1 aggregation + ELU
__global__ __launch_bounds__(256) void k_agg1(const int* csr, const int* off,
                                              const float* h1, const float* as1,
                                              const float* ad1, float* h1e) {
    const int lane = threadIdx.x & 63;
    const int n = (blockIdx.x * blockDim.x + threadIdx.x) >> 6;
    if (n >= N_NODES) return;
    const int beg = off[n], end = off[n + 1];
    const int hh = lane & 7;    // head for pass 1 (8 edges x 8 heads per iter)
    const int h0 = lane >> 3;   // head owning this lane's feature column
    // pass 1: per-head softmax denominators
    float adst1 = ad1[n * HEADS + hh];
    float dsum = 0.f;
    for (int i = beg + (lane >> 3); i < end; i += 8) {
        int s = csr[i];
        dsum += __expf(leaky(as1[s * HEADS + hh] + adst1));
    }
    dsum += __shfl_xor(dsum, 8, 64);
    dsum += __shfl_xor(dsum, 16, 64);
    dsum += __shfl_xor(dsum, 32, 64);
    float rd = 1.f / (dsum + 1e-16f);
    float rdn = __shfl(rd, h0, 64);   // denom reciprocal for head h0
    // pass 2: weighted aggregation (recompute exp; cheaper than storing E*H)
    float adst2 = ad1[n * HEADS + h0];
    float acc = 0.f;
    for (int i = beg; i < end; i++) {
        int s = csr[i];
        float al = __expf(leaky(as1[s * HEADS + h0] + adst2)) * rdn;
        acc = fmaf(al, h1[(size_t)s * D1 + lane], acc);
    }
    float o = acc > 0.f ? acc : (__expf(acc) - 1.f);   // ELU(alpha=1)
    h1e[(size_t)n * D1 + lane] = o;
}

// ---------------------------------------------------------------- GEMM2: h2 = h1e @ W2, + alpha halves
__global__ __launch_bounds__(256) void k_gemm2(const float* h1e, const float* W2f,
                                               const float* A2Sf, const float* A2Df,
                                               float* h2, float* as2, float* ad2) {
    const int lane = threadIdx.x & 63;
    const int wave = (blockIdx.x * blockDim.x + threadIdx.x) >> 6;
    const int n0 = wave * 8;
    if (n0 >= N_NODES) return;
    float acc[8];
#pragma unroll
    for (int r = 0; r < 8; r++) acc[r] = 0.f;
    const bool act = lane < NC;
    for (int k = 0; k < D1; k += 4) {
        float w0 = act ? W2f[(k + 0) * NC + lane] : 0.f;
        float w1 = act ? W2f[(k + 1) * NC + lane] : 0.f;
        float w2 = act ? W2f[(k + 2) * NC + lane] : 0.f;
        float w3 = act ? W2f[(k + 3) * NC + lane] : 0.f;
#pragma unroll
        for (int r = 0; r < 8; r++) {
            float4 hv = *(const float4*)(h1e + (size_t)(n0 + r) * D1 + k);
            acc[r] = fmaf(hv.x, w0, acc[r]);
            acc[r] = fmaf(hv.y, w1, acc[r]);
            acc[r] = fmaf(hv.z, w2, acc[r]);
            acc[r] = fmaf(hv.w, w3, acc[r]);
        }
    }
    float a_s = act ? A2Sf[lane] : 0.f;
    float a_d = act ? A2Df[lane] : 0.f;
#pragma unroll
    for (int r = 0; r < 8; r++) {
        int n = n0 + r;
        if (act) h2[(size_t)n * NC + lane] = acc[r];
        float ts = acc[r] * a_s, td = acc[r] * a_d;
#pragma unroll
        for (int o = 1; o < 64; o <<= 1) {
            ts += __shfl_xor(ts, o, 64);
            td += __shfl_xor(td, o, 64);
        }
        if (lane == 0) { as2[n] = ts; ad2[n] = td; }
    }
}

// ---------------------------------------------------------------- layer-2 aggregation + log_softmax
__global__ __launch_bounds__(256) void k_agg2(const int* csr, const int* off,
                                              const float* h2, const float* as2,
                                              const float* ad2, const int* flags,
                                              void* out) {
    const int lane = threadIdx.x & 63;
    const int n = (blockIdx.x * blockDim.x + threadIdx.x) >> 6;
    if (n >= N_NODES) return;
    const int beg = off[n], end = off[n + 1];
    const float adst = ad2[n];
    float dsum = 0.f;
    for (int i = beg + lane; i < end; i += 64) {
        int s = csr[i];
        dsum += __expf(leaky(as2[s] + adst));
    }
#pragma unroll
    for (int o = 1; o < 64; o <<= 1) dsum += __shfl_xor(dsum, o, 64);
    float rd = 1.f / (dsum + 1e-16f);
    const bool act = lane < NC;
    float acc = 0.f;
    for (int i = beg; i < end; i++) {
        int s = csr[i];
        float al = __expf(leaky(as2[s] + adst)) * rd;
        if (act) acc = fmaf(al, h2[(size_t)s * NC + lane], acc);
    }
    // log_softmax over the 41 classes
    float v = act ? acc : -INFINITY;
    float m = v;
#pragma unroll
    for (int o = 1; o < 64; o <<= 1) m = fmaxf(m, __shfl_xor(m, o, 64));
    float ex = act ? __expf(acc - m) : 0.f;
#pragma unroll
    for (int o = 1; o < 64; o <<= 1) ex += __shfl_xor(ex, o, 64);
    float res = acc - m - __logf(ex);
    if (act) {
        if (flags[0])
            ((float*)out)[(size_t)n * NC + lane] = res;
        else
            ((__hip_bfloat16*)out)[(size_t)n * NC + lane] = __float2bfloat16(res);
    }
}

// ---------------------------------------------------------------- host
extern "C" void kernel_launch(void* const* d_in, const int* in_sizes, int n_in,
                              void* d_out, int out_size, void* d_ws, size_t ws_size,
                              hipStream_t stream) {
    char* p = (char*)d_ws;
    auto alloc = [&](size_t bytes) -> void* {
        void* r = (void*)p;
        p += (bytes + 255) & ~(size_t)255;
        return r;
    };
    int* flags  = (int*)alloc(16);
    float* W1f  = (float*)alloc((size_t)F_IN * D1 * 4);
    float* A1Sf = (float*)alloc(HEADS * HID * 4);
    float* A1Df = (float*)alloc(HEADS * HID * 4);
    float* W2f  = (float*)alloc((size_t)D1 * NC * 4);
    float* A2Sf = (float*)alloc(NC * 4);
    float* A2Df = (float*)alloc(NC * 4);
    float* h1   = (float*)alloc((size_t)N_NODES * D1 * 4);
    float* as1  = (float*)alloc((size_t)N_NODES * HEADS * 4);
    float* ad1  = (float*)alloc((size_t)N_NODES * HEADS * 4);
    float* h1e  = (float*)alloc((size_t)N_NODES * D1 * 4);
    float* h2   = (float*)alloc((size_t)N_NODES * NC * 4);
    float* as2  = (float*)alloc((size_t)N_NODES * 4);
    float* ad2  = (float*)alloc((size_t)N_NODES * 4);
    int* deg    = (int*)alloc((size_t)N_NODES * 4);
    int* off    = (int*)alloc((size_t)(N_NODES + 1) * 4);
    int* pos    = (int*)alloc((size_t)N_NODES * 4);
    int* bsum   = (int*)alloc((size_t)NCHUNK * 4);
    int* csr    = (int*)alloc((size_t)N_EDGES * 4);

    hipMemsetAsync(deg, 0, (size_t)N_NODES * 4, stream);

    k_detect_convert<<<1, 256, 0, stream>>>(d_in[0], d_in[1], d_in[2], d_in[3],
                                            d_in[4], d_in[5], d_in[6], d_in[7],
                                            W1f, A1Sf, A1Df, W2f, A2Sf, A2Df, flags);
    k_hist<<<4096, 256, 0, stream>>>(d_in[1], flags, deg);
    k_scan1<<<NCHUNK, 256, 0, stream>>>(deg, bsum);
    k_scan2<<<1, 64, 0, stream>>>(bsum, off);
    k_scan3<<<NCHUNK, 256, 0, stream>>>(deg, bsum, off, pos);
    k_scatter<<<4096, 256, 0, stream>>>(d_in[1], flags, pos, csr);

    // 6250 waves x 16 rows, 4 waves/block
    k_gemm1<<<1563, 256, 0, stream>>>(d_in[0], flags, W1f, A1Sf, A1Df, h1, as1, ad1);
    k_agg1<<<25000, 256, 0, stream>>>(csr, off, h1, as1, ad1, h1e);
    k_gemm2<<<3125, 256, 0, stream>>>(h1e, W2f, A2Sf, A2Df, h2, as2, ad2);
    k_agg2<<<25000, 256, 0, stream>>>(csr, off, h2, as2, ad2, flags, d_out);
}

// Round 2
// 1235.308 us; speedup vs baseline: 1.9354x; 1.9354x over previous
//
#include <hip/hip_runtime.h>
#include <hip/hip_bf16.h>
#include <math.h>

// GAT 2-layer inference on MI355X.
// R1: gemm1 rewritten lane=row with LDS-staged x tile (was broadcast-load
// latency-bound: VALUBusy 12%, hbm 1.7%); agg loops 4x unrolled for MLP.

#define DEV __device__ __forceinline__

constexpr int N_NODES = 100000;
constexpr int N_EDGES = 3200000;
constexpr int F_IN    = 500;
constexpr int HEADS   = 8;
constexpr int HID     = 8;
constexpr int D1      = HEADS * HID;   // 64
constexpr int NC      = 41;

constexpr int CHUNK  = 1024;
constexpr int NCHUNK = (N_NODES + CHUNK - 1) / CHUNK;   // 98

constexpr int LDSP = 68;   // padded f32 row stride for x tile (16B-aligned, bank-clean)

DEV float bf2f(unsigned short u) {
    return __uint_as_float(((unsigned int)u) << 16);
}
DEV float leaky(float e) { return e > 0.f ? e : 0.2f * e; }

// ---------------------------------------------------------------- detect + convert weights
__global__ void k_detect_convert(const void* xraw, const void* eraw,
                                 const void* w1, const void* a1s, const void* a1d,
                                 const void* w2, const void* a2s, const void* a2d,
                                 float* W1f, float* A1Sf, float* A1Df,
                                 float* W2f, float* A2Sf, float* A2Df,
                                 int* flags) {
    __shared__ int sf;
    if (threadIdx.x == 0) {
        const unsigned short* xu = (const unsigned short*)xraw;
        int valid = 0;
        for (int i = 0; i < 64; i++) {
            unsigned short v = xu[2 * i];
            int e = (v >> 7) & 0xFF;
            if (e == 0 || (e >= 90 && e <= 150)) valid++;
        }
        int xf32 = (valid < 56) ? 1 : 0;
        const unsigned int* eu = (const unsigned int*)eraw;
        int zeros = 0;
        for (int k = 0; k < 64; k++)
            if (eu[2 * k + 1] == 0u) zeros++;
        int e64 = (zeros == 64) ? 1 : 0;
        flags[0] = xf32;
        flags[1] = e64;
        sf = xf32;
    }
    __syncthreads();
    bool f32 = (sf != 0);
    auto conv = [&](const void* src, float* dst, int n) {
        if (f32) {
            const float* s = (const float*)src;
            for (int i = threadIdx.x; i < n; i += blockDim.x) dst[i] = s[i];
        } else {
            const unsigned short* s = (const unsigned short*)src;
            for (int i = threadIdx.x; i < n; i += blockDim.x) dst[i] = bf2f(s[i]);
        }
    };
    conv(w1, W1f, F_IN * D1);
    conv(a1s, A1Sf, HEADS * HID);
    conv(a1d, A1Df, HEADS * HID);
    conv(w2, W2f, D1 * NC);
    conv(a2s, A2Sf, NC);
    conv(a2d, A2Df, NC);
}

// ---------------------------------------------------------------- CSR build
__global__ void k_hist(const void* eraw, const int* flags, int* deg) {
    bool e64 = flags[1] != 0;
    const unsigned int* eu = (const unsigned int*)eraw;
    int i = blockIdx.x * blockDim.x + threadIdx.x;
    int stride = gridDim.x * blockDim.x;
    for (; i < N_EDGES; i += stride) {
        int dst = e64 ? (int)eu[2 * (N_EDGES + i)] : (int)eu[N_EDGES + i];
        atomicAdd(&deg[dst], 1);
    }
}

__global__ void k_scan1(const int* deg, int* bsum) {
    __shared__ int lds[256];
    int base = blockIdx.x * CHUNK + threadIdx.x * 4;
    int s = 0;
    for (int r = 0; r < 4; r++) {
        int i = base + r;
        if (i < N_NODES) s += deg[i];
    }
    lds[threadIdx.x] = s;
    __syncthreads();
    for (int o = 128; o > 0; o >>= 1) {
        if (threadIdx.x < o) lds[threadIdx.x] += lds[threadIdx.x + o];
        __syncthreads();
    }
    if (threadIdx.x == 0) bsum[blockIdx.x] = lds[0];
}

__global__ void k_scan2(int* bsum, int* off) {
    if (threadIdx.x == 0) {
        int run = 0;
        for (int c = 0; c < NCHUNK; c++) {
            int v = bsum[c];
            bsum[c] = run;
            run += v;
        }
        off[N_NODES] = run;
    }
}

__global__ void k_scan3(const int* deg, const int* bsum, int* off, int* pos) {
    __shared__ int lds[256];
    int t = threadIdx.x;
    int base = blockIdx.x * CHUNK + t * 4;
    int v[4];
    int s = 0;
    for (int r = 0; r < 4; r++) {
        int i = base + r;
        v[r] = (i < N_NODES) ? deg[i] : 0;
        s += v[r];
    }
    lds[t] = s;
    __syncthreads();
    for (int o = 1; o < 256; o <<= 1) {
        int add = (t >= o) ? lds[t - o] : 0;
        __syncthreads();
        lds[t] += add;
        __syncthreads();
    }
    int excl = bsum[blockIdx.x] + ((t > 0) ? lds[t - 1] : 0);
    for (int r = 0; r < 4; r++) {
        int i = base + r;
        if (i < N_NODES) { off[i] = excl; pos[i] = excl; }
        excl += v[r];
    }
}

__global__ void k_scatter(const void* eraw, const int* flags, int* pos, int* csr) {
    bool e64 = flags[1] != 0;
    const unsigned int* eu = (const unsigned int*)eraw;
    int i = blockIdx.x * blockDim.x + threadIdx.x;
    int stride = gridDim.x * blockDim.x;
    for (; i < N_EDGES; i += stride) {
        int src = e64 ? (int)eu[2 * i] : (int)eu[i];
        int dst = e64 ? (int)eu[2 * (N_EDGES + i)] : (int)eu[N_EDGES + i];
        int slot = atomicAdd(&pos[dst], 1);
        csr[slot] = src;
    }
}

// ---------------------------------------------------------------- GEMM1 (lane=row, LDS x tile)
// Block: 256 thr = 4 waves; 64 rows x 64 cols per block. Wave w owns cols
// [16w,16w+16) = heads 2w,2w+1. x tile staged bf16->f32 in LDS (stride 68).
// W reads are wave-uniform -> s_load; inner step = 1 ds_read_b128 + 64 fma.

template <bool XF32>
DEV void stage_tile(const void* xraw, float* ldsx, int r0, int k0, bool tail) {
    int t = threadIdx.x;
    int srow = t >> 2, sseg = t & 3;
    int row_g = r0 + srow;
    if (row_g >= N_NODES) return;
    float* dst = ldsx + srow * LDSP + sseg * 16;
    int nv = tail ? (sseg < 3 ? 4 : 1) : 4;
    if (XF32) {
        const float4* src = (const float4*)((const float*)xraw + (size_t)row_g * F_IN + k0 + sseg * 16);
        for (int j = 0; j < nv; j++) {
            float4 v = src[j];
            *(float4*)(dst + 4 * j) = v;
        }
    } else {
        const ushort4* src = (const ushort4*)((const unsigned short*)xraw + (size_t)row_g * F_IN + k0 + sseg * 16);
        for (int j = 0; j < nv; j++) {
            ushort4 u = src[j];
            float4 v = make_float4(bf2f(u.x), bf2f(u.y), bf2f(u.z), bf2f(u.w));
            *(float4*)(dst + 4 * j) = v;
        }
    }
}

template <int NG>
DEV void compute_tile(const float* ldsx, const float* __restrict__ W1f,
                      int k0, int c0, int lane, float acc[16]) {
#pragma unroll
    for (int g = 0; g < NG; g++) {
        float4 xv = *(const float4*)(ldsx + lane * LDSP + g * 4);
        const float* w0 = W1f + (size_t)(k0 + g * 4 + 0) * D1 + c0;
        const float* w1 = W1f + (size_t)(k0 + g * 4 + 1) * D1 + c0;
        const float* w2 = W1f + (size_t)(k0 + g * 4 + 2) * D1 + c0;
        const float* w3 = W1f + (size_t)(k0 + g * 4 + 3) * D1 + c0;
#pragma unroll
        for (int c = 0; c < 16; c++) {
            acc[c] = fmaf(xv.x, w0[c], acc[c]);
            acc[c] = fmaf(xv.y, w1[c], acc[c]);
            acc[c] = fmaf(xv.z, w2[c], acc[c]);
            acc[c] = fmaf(xv.w, w3[c], acc[c]);
        }
    }
}

template <bool XF32>
DEV void gemm1_body(const void* xraw, const float* __restrict__ W1f,
                    const float* A1Sf, const float* A1Df,
                    float* h1, float* as1, float* ad1,
                    float* ldsx, int r0) {
    const int lane = threadIdx.x & 63;
    const int wid = __builtin_amdgcn_readfirstlane(threadIdx.x >> 6);
    const int c0 = wid * 16;
    float acc[16];
#pragma unroll
    for (int c = 0; c < 16; c++) acc[c] = 0.f;

    for (int tile = 0; tile < 7; tile++) {
        __syncthreads();
        stage_tile<XF32>(xraw, ldsx, r0, tile * 64, false);
        __syncthreads();
        compute_tile<16>(ldsx, W1f, tile * 64, c0, lane, acc);
    }
    __syncthreads();
    stage_tile<XF32>(xraw, ldsx, r0, 448, true);
    __syncthreads();
    compute_tile<13>(ldsx, W1f, 448, c0, lane, acc);   // 448 + 52 = 500

    const int row = r0 + lane;
    if (row >= N_NODES) return;
#pragma unroll
    for (int j = 0; j < 4; j++) {
        float4 v = make_float4(acc[4 * j], acc[4 * j + 1], acc[4 * j + 2], acc[4 * j + 3]);
        *(float4*)(h1 + (size_t)row * D1 + c0 + 4 * j) = v;
    }
#pragma unroll
    for (int hh = 0; hh < 2; hh++) {
        int h = 2 * wid + hh;
        float ts = 0.f, td = 0.f;
#pragma unroll
        for (int d = 0; d < 8; d++) {
            ts = fmaf(acc[8 * hh + d], A1Sf[h * 8 + d], ts);
            td = fmaf(acc[8 * hh + d], A1Df[h * 8 + d], td);
        }
        as1[row * HEADS + h] = ts;
        ad1[row * HEADS + h] = td;
    }
}

__global__ __launch_bounds__(256) void k_gemm1(const void* xraw, const int* flags,
                                               const float* W1f, const float* A1Sf,
                                               const float* A1Df, float* h1,
                                               float* as1, float* ad1) {
    __shared__ float ldsx[64 * LDSP];
    int r0 = blockIdx.x * 64;
    if (flags[0])
        gemm1_body<true>(xraw, W1f, A1Sf, A1Df, h1, as1, ad1, ldsx, r0);
    else
        gemm1_body<false>(xraw, W1f, A1Sf, A1Df, h1, as1, ad1, ldsx, r0);
}

// ---------------------------------------------------------------- layer-1 aggregation + ELU
__global__ __launch_bounds__(256) void k_agg1(const int* __restrict__ csr,
                                              const int* __restrict__ off,
                                              const float* __restrict__ h1,
                                              const float* __restrict__ as1,
                                              const float* __restrict__ ad1,
                                              float* __restrict__ h1e) {
    const int lane = threadIdx.x & 63;
    const int n = (blockIdx.x * blockDim.x + threadIdx.x) >> 6;
    if (n >= N_NODES) return;
    const int beg = off[n], end = off[n + 1];
    const int hh = lane & 7;
    const int h0 = lane >> 3;
    // pass 1: per-head softmax denominators (8 edges x 8 heads per iter)
    float adst1 = ad1[n * HEADS + hh];
    float dsum = 0.f;
    for (int i = beg + (lane >> 3); i < end; i += 8) {
        int s = csr[i];
        dsum += __expf(leaky(as1[s * HEADS + hh] + adst1));
    }
    dsum += __shfl_xor(dsum, 8, 64);
    dsum += __shfl_xor(dsum, 16, 64);
    dsum += __shfl_xor(dsum, 32, 64);
    float rd = 1.f / (dsum + 1e-16f);
    float rdn = __shfl(rd, h0, 64);
    // pass 2: weighted aggregation, 4x unrolled for memory-level parallelism
    float adst2 = ad1[n * HEADS + h0];
    float acc = 0.f;
    int i = beg;
    for (; i + 4 <= end; i += 4) {
        int s0 = csr[i], s1 = csr[i + 1], s2 = csr[i + 2], s3 = csr[i + 3];
        float a0 = as1[s0 * HEADS + h0], a1 = as1[s1 * HEADS + h0];
        float a2 = as1[s2 * HEADS + h0], a3 = as1[s3 * HEADS + h0];
        float g0 = h1[(size_t)s0 * D1 + lane], g1 = h1[(size_t)s1 * D1 + lane];
        float g2 = h1[(size_t)s2 * D1 + lane], g3 = h1[(size_t)s3 * D1 + lane];
        acc = fmaf(__expf(leaky(a0 + adst2)) * rdn, g0, acc);
        acc = fmaf(__expf(leaky(a1 + adst2)) * rdn, g1, acc);
        acc = fmaf(__expf(leaky(a2 + adst2)) * rdn, g2, acc);
        acc = fmaf(__expf(leaky(a3 + adst2)) * rdn, g3, acc);
    }
    for (; i < end; i++) {
        int s = csr[i];
        float al = __expf(leaky(as1[s * HEADS + h0] + adst2)) * rdn;
        acc = fmaf(al, h1[(size_t)s * D1 + lane], acc);
    }
    float o = acc > 0.f ? acc : (__expf(acc) - 1.f);   // ELU
    h1e[(size_t)n * D1 + lane] = o;
}

// ---------------------------------------------------------------- GEMM2: h2 = h1e @ W2, + alpha halves
__global__ __launch_bounds__(256) void k_gemm2(const float* __restrict__ h1e,
                                               const float* __restrict__ W2f,
                                               const float* A2Sf, const float* A2Df,
                                               float* h2, float* as2, float* ad2) {
    const int lane = threadIdx.x & 63;
    const int wave = (blockIdx.x * blockDim.x + threadIdx.x) >> 6;
    const int n0 = wave * 8;
    if (n0 >= N_NODES) return;
    float acc[8];
#pragma unroll
    for (int r = 0; r < 8; r++) acc[r] = 0.f;
    const bool act = lane < NC;
    for (int k = 0; k < D1; k += 4) {
        float w0 = act ? W2f[(k + 0) * NC + lane] : 0.f;
        float w1 = act ? W2f[(k + 1) * NC + lane] : 0.f;
        float w2 = act ? W2f[(k + 2) * NC + lane] : 0.f;
        float w3 = act ? W2f[(k + 3) * NC + lane] : 0.f;
#pragma unroll
        for (int r = 0; r < 8; r++) {
            float4 hv = *(const float4*)(h1e + (size_t)(n0 + r) * D1 + k);
            acc[r] = fmaf(hv.x, w0, acc[r]);
            acc[r] = fmaf(hv.y, w1, acc[r]);
            acc[r] = fmaf(hv.z, w2, acc[r]);
            acc[r] = fmaf(hv.w, w3, acc[r]);
        }
    }
    float a_s = act ? A2Sf[lane] : 0.f;
    float a_d = act ? A2Df[lane] : 0.f;
#pragma unroll
    for (int r = 0; r < 8; r++) {
        int n = n0 + r;
        if (act) h2[(size_t)n * NC + lane] = acc[r];
        float ts = acc[r] * a_s, td = acc[r] * a_d;
#pragma unroll
        for (int o = 1; o < 64; o <<= 1) {
            ts += __shfl_xor(ts, o, 64);
            td += __shfl_xor(td, o, 64);
        }
        if (lane == 0) { as2[n] = ts; ad2[n] = td; }
    }
}

// ---------------------------------------------------------------- layer-2 aggregation + log_softmax
__global__ __launch_bounds__(256) void k_agg2(const int* __restrict__ csr,
                                              const int* __restrict__ off,
                                              const float* __restrict__ h2,
                                              const float* __restrict__ as2,
                                              const float* __restrict__ ad2,
                                              const int* flags, void* out) {
    const int lane = threadIdx.x & 63;
    const int n = (blockIdx.x * blockDim.x + threadIdx.x) >> 6;
    if (n >= N_NODES) return;
    const int beg = off[n], end = off[n + 1];
    const float adst = ad2[n];
    float dsum = 0.f;
    for (int i = beg + lane; i < end; i += 64) {
        int s = csr[i];
        dsum += __expf(leaky(as2[s] + adst));
    }
#pragma unroll
    for (int o = 1; o < 64; o <<= 1) dsum += __shfl_xor(dsum, o, 64);
    float rd = 1.f / (dsum + 1e-16f);
    const bool act = lane < NC;
    float acc = 0.f;
    int i = beg;
    for (; i + 4 <= end; i += 4) {
        int s0 = csr[i], s1 = csr[i + 1], s2 = csr[i + 2], s3 = csr[i + 3];
        float a0 = as2[s0], a1 = as2[s1], a2 = as2[s2], a3 = as2[s3];
        float g0 = 0.f, g1 = 0.f, g2 = 0.f, g3 = 0.f;
        if (act) {
            g0 = h2[(size_t)s0 * NC + lane];
            g1 = h2[(size_t)s1 * NC + lane];
            g2 = h2[(size_t)s2 * NC + lane];
            g3 = h2[(size_t)s3 * NC + lane];
        }
        acc = fmaf(__expf(leaky(a0 + adst)) * rd, g0, acc);
        acc = fmaf(__expf(leaky(a1 + adst)) * rd, g1, acc);
        acc = fmaf(__expf(leaky(a2 + adst)) * rd, g2, acc);
        acc = fmaf(__expf(leaky(a3 + adst)) * rd, g3, acc);
    }
    for (; i < end; i++) {
        int s = csr[i];
        float al = __expf(leaky(as2[s] + adst)) * rd;
        if (act) acc = fmaf(al, h2[(size_t)s * NC + lane], acc);
    }
    float v = act ? acc : -INFINITY;
    float m = v;
#pragma unroll
    for (int o = 1; o < 64; o <<= 1) m = fmaxf(m, __shfl_xor(m, o, 64));
    float ex = act ? __expf(acc - m) : 0.f;
#pragma unroll
    for (int o = 1; o < 64; o <<= 1) ex += __shfl_xor(ex, o, 64);
    float res = acc - m - __logf(ex);
    if (act) {
        if (flags[0])
            ((float*)out)[(size_t)n * NC + lane] = res;
        else
            ((__hip_bfloat16*)out)[(size_t)n * NC + lane] = __float2bfloat16(res);
    }
}

// ---------------------------------------------------------------- host
extern "C" void kernel_launch(void* const* d_in, const int* in_sizes, int n_in,
                              void* d_out, int out_size, void* d_ws, size_t ws_size,
                              hipStream_t stream) {
    char* p = (char*)d_ws;
    auto alloc = [&](size_t bytes) -> void* {
        void* r = (void*)p;
        p += (bytes + 255) & ~(size_t)255;
        return r;
    };
    int* flags  = (int*)alloc(16);
    float* W1f  = (float*)alloc((size_t)F_IN * D1 * 4);
    float* A1Sf = (float*)alloc(HEADS * HID * 4);
    float* A1Df = (float*)alloc(HEADS * HID * 4);
    float* W2f  = (float*)alloc((size_t)D1 * NC * 4);
    float* A2Sf = (float*)alloc(NC * 4);
    float* A2Df = (float*)alloc(NC * 4);
    float* h1   = (float*)alloc((size_t)N_NODES * D1 * 4);
    float* as1  = (float*)alloc((size_t)N_NODES * HEADS * 4);
    float* ad1  = (float*)alloc((size_t)N_NODES * HEADS * 4);
    float* h1e  = (float*)alloc((size_t)N_NODES * D1 * 4);
    float* h2   = (float*)alloc((size_t)N_NODES * NC * 4);
    float* as2  = (float*)alloc((size_t)N_NODES * 4);
    float* ad2  = (float*)alloc((size_t)N_NODES * 4);
    int* deg    = (int*)alloc((size_t)N_NODES * 4);
    int* off    = (int*)alloc((size_t)(N_NODES + 1) * 4);
    int* pos    = (int*)alloc((size_t)N_NODES * 4);
    int* bsum   = (int*)alloc((size_t)NCHUNK * 4);
    int* csr    = (int*)alloc((size_t)N_EDGES * 4);

    hipMemsetAsync(deg, 0, (size_t)N_NODES * 4, stream);

    k_detect_convert<<<1, 256, 0, stream>>>(d_in[0], d_in[1], d_in[2], d_in[3],
                                            d_in[4], d_in[5], d_in[6], d_in[7],
                                            W1f, A1Sf, A1Df, W2f, A2Sf, A2Df, flags);
    k_hist<<<4096, 256, 0, stream>>>(d_in[1], flags, deg);
    k_scan1<<<NCHUNK, 256, 0, stream>>>(deg, bsum);
    k_scan2<<<1, 64, 0, stream>>>(bsum, off);
    k_scan3<<<NCHUNK, 256, 0, stream>>>(deg, bsum, off, pos);
    k_scatter<<<4096, 256, 0, stream>>>(d_in[1], flags, pos, csr);

    k_gemm1<<<1563, 256, 0, stream>>>(d_in[0], flags, W1f, A1Sf, A1Df, h1, as1, ad1);
    k_agg1<<<25000, 256, 0, stream>>>(csr, off, h1, as1, ad1, h1e);
    k_gemm2<<<3125, 256, 0, stream>>>(h1e, W2f, A2Sf, A2Df, h2, as2, ad2);
    k_agg2<<<25000, 256, 0, stream>>>(csr, off, h2, as2, ad2, flags, d_out);
}

// Round 3
// 824.093 us; speedup vs baseline: 2.9012x; 1.4990x over previous
//
#include <hip/hip_runtime.h>
#include <hip/hip_bf16.h>
#include <math.h>

// GAT 2-layer inference on MI355X.
// R1: gemm1 lane=row + LDS tile (broadcast-load fix).
// R2: CSR build via bucketed scatter (was 195MB write-amp, 300us) -> staged
//     locality-aware build with LDS per-node counters; agg1/agg2 fused to a
//     single edge sweep (unnormalized sums, divide at end); gemm2 thread=row.

#define DEV __device__ __forceinline__

constexpr int N_NODES = 100000;
constexpr int N_EDGES = 3200000;
constexpr int F_IN    = 500;
constexpr int HEADS   = 8;
constexpr int HID     = 8;
constexpr int D1      = HEADS * HID;   // 64
constexpr int NC      = 41;

constexpr int LDSP = 68;   // padded f32 row stride for gemm1 x tile

// bucketed CSR build
constexpr int NB    = 196;     // buckets of 512 nodes (dst >> 9)
constexpr int BCAP  = 20480;   // staging capacity per bucket (avg 16327, 32 sigma headroom)
constexpr int SEPT  = 16;      // edges per thread in bucket_scatter
constexpr int SCHUNK = 256 * SEPT;   // 4096 edges per block

DEV float bf2f(unsigned short u) {
    return __uint_as_float(((unsigned int)u) << 16);
}
DEV float leaky(float e) { return e > 0.f ? e : 0.2f * e; }

// ---------------------------------------------------------------- detect + convert weights
__global__ void k_detect_convert(const void* xraw, const void* eraw,
                                 const void* w1, const void* a1s, const void* a1d,
                                 const void* w2, const void* a2s, const void* a2d,
                                 float* W1f, float* A1Sf, float* A1Df,
                                 float* W2f, float* A2Sf, float* A2Df,
                                 int* flags) {
    __shared__ int sf;
    if (threadIdx.x == 0) {
        const unsigned short* xu = (const unsigned short*)xraw;
        int valid = 0;
        for (int i = 0; i < 64; i++) {
            unsigned short v = xu[2 * i];
            int e = (v >> 7) & 0xFF;
            if (e == 0 || (e >= 90 && e <= 150)) valid++;
        }
        int xf32 = (valid < 56) ? 1 : 0;
        const unsigned int* eu = (const unsigned int*)eraw;
        int zeros = 0;
        for (int k = 0; k < 64; k++)
            if (eu[2 * k + 1] == 0u) zeros++;
        int e64 = (zeros == 64) ? 1 : 0;
        flags[0] = xf32;
        flags[1] = e64;
        sf = xf32;
    }
    __syncthreads();
    bool f32 = (sf != 0);
    auto conv = [&](const void* src, float* dst, int n) {
        if (f32) {
            const float* s = (const float*)src;
            for (int i = threadIdx.x; i < n; i += blockDim.x) dst[i] = s[i];
        } else {
            const unsigned short* s = (const unsigned short*)src;
            for (int i = threadIdx.x; i < n; i += blockDim.x) dst[i] = bf2f(s[i]);
        }
    };
    conv(w1, W1f, F_IN * D1);
    conv(a1s, A1Sf, HEADS * HID);
    conv(a1d, A1Df, HEADS * HID);
    conv(w2, W2f, D1 * NC);
    conv(a2s, A2Sf, NC);
    conv(a2d, A2Df, NC);
}

// ---------------------------------------------------------------- CSR build, pass 1:
// bucket edges by dst>>9 into fixed-capacity staging regions. Per-block LDS
// hist -> one global atomic per (block,bucket) -> run-contiguous packed writes.
__global__ __launch_bounds__(256) void k_bucket_scatter(const void* eraw, const int* flags,
                                                        int* bucket_cnt, unsigned int* staging) {
    __shared__ int bh[NB];
    const int t = threadIdx.x;
    for (int i = t; i < NB; i += 256) bh[i] = 0;
    __syncthreads();
    const bool e64 = flags[1] != 0;
    const unsigned int* eu = (const unsigned int*)eraw;
    const int e0 = blockIdx.x * SCHUNK;
    int sv[SEPT], dv[SEPT];
#pragma unroll
    for (int k = 0; k < SEPT; k++) {
        int i = e0 + k * 256 + t;
        if (i < N_EDGES) {
            if (e64) { sv[k] = (int)eu[2 * i]; dv[k] = (int)eu[2 * (N_EDGES + i)]; }
            else     { sv[k] = (int)eu[i];     dv[k] = (int)eu[N_EDGES + i]; }
            atomicAdd(&bh[dv[k] >> 9], 1);
        } else dv[k] = -1;
    }
    __syncthreads();
    for (int i = t; i < NB; i += 256) {
        int c = bh[i];
        int base = c ? atomicAdd(&bucket_cnt[i], c) : 0;
        bh[i] = i * BCAP + base;   // global staging cursor for this block's run
    }
    __syncthreads();
#pragma unroll
    for (int k = 0; k < SEPT; k++) {
        if (dv[k] >= 0) {
            int b = dv[k] >> 9;
            int slot = atomicAdd(&bh[b], 1);
            staging[slot] = (unsigned)sv[k] | ((unsigned)(dv[k] & 511) << 17);
        }
    }
}

// pass 2: exclusive scan of bucket counts -> CSR-space bucket bases
__global__ void k_cscan(const int* bucket_cnt, int* cbase, int* off) {
    __shared__ int s[256];
    int t = threadIdx.x;
    s[t] = (t < NB) ? bucket_cnt[t] : 0;
    __syncthreads();
    for (int o = 1; o < 256; o <<= 1) {
        int v = (t >= o) ? s[t - o] : 0;
        __syncthreads();
        s[t] += v;
        __syncthreads();
    }
    if (t < NB) cbase[t + 1] = s[t];
    if (t == 0) { cbase[0] = 0; off[N_NODES] = N_EDGES; }
}

// pass 3: one block per bucket; per-node deg/offset/cursor in LDS; csr writes
// confined to a ~65KB contiguous region (single-XCD L2 locality).
__global__ __launch_bounds__(512) void k_csr_build(const unsigned int* __restrict__ staging,
                                                   const int* __restrict__ bucket_cnt,
                                                   const int* __restrict__ cbase,
                                                   int* __restrict__ off, int* __restrict__ csr) {
    __shared__ int sdeg[512];
    __shared__ int scur[512];
    const int t = threadIdx.x;
    const int b = blockIdx.x;
    const int n0 = b << 9;
    const int start = b * BCAP;
    const int end = start + bucket_cnt[b];
    const int base = cbase[b];
    sdeg[t] = 0;
    __syncthreads();
    for (int i = start + t; i < end; i += 512)
        atomicAdd(&sdeg[staging[i] >> 17], 1);
    __syncthreads();
    int d = sdeg[t];
    for (int o = 1; o < 512; o <<= 1) {   // inclusive scan, in place
        int v = (t >= o) ? sdeg[t - o] : 0;
        __syncthreads();
        sdeg[t] += v;
        __syncthreads();
    }
    int excl = sdeg[t] - d;
    if (n0 + t < N_NODES) off[n0 + t] = base + excl;
    scur[t] = base + excl;
    __syncthreads();
    for (int i = start + t; i < end; i += 512) {
        unsigned v = staging[i];
        int slot = atomicAdd(&scur[v >> 17], 1);
        csr[slot] = (int)(v & 0x1FFFFu);
    }
}

// ---------------------------------------------------------------- GEMM1 (lane=row, LDS x tile)
template <bool XF32>
DEV void stage_tile(const void* xraw, float* ldsx, int r0, int k0, bool tail) {
    int t = threadIdx.x;
    int srow = t >> 2, sseg = t & 3;
    int row_g = r0 + srow;
    if (row_g >= N_NODES) return;
    float* dst = ldsx + srow * LDSP + sseg * 16;
    int nv = tail ? (sseg < 3 ? 4 : 1) : 4;
    if (XF32) {
        const float4* src = (const float4*)((const float*)xraw + (size_t)row_g * F_IN + k0 + sseg * 16);
        for (int j = 0; j < nv; j++) {
            float4 v = src[j];
            *(float4*)(dst + 4 * j) = v;
        }
    } else {
        const ushort4* src = (const ushort4*)((const unsigned short*)xraw + (size_t)row_g * F_IN + k0 + sseg * 16);
        for (int j = 0; j < nv; j++) {
            ushort4 u = src[j];
            float4 v = make_float4(bf2f(u.x), bf2f(u.y), bf2f(u.z), bf2f(u.w));
            *(float4*)(dst + 4 * j) = v;
        }
    }
}

template <int NG>
DEV void compute_tile(const float* ldsx, const float* __restrict__ W1f,
                      int k0, int c0, int lane, float acc[16]) {
#pragma unroll
    for (int g = 0; g < NG; g++) {
        float4 xv = *(const float4*)(ldsx + lane * LDSP + g * 4);
        const float* w0 = W1f + (size_t)(k0 + g * 4 + 0) * D1 + c0;
        const float* w1 = W1f + (size_t)(k0 + g * 4 + 1) * D1 + c0;
        const float* w2 = W1f + (size_t)(k0 + g * 4 + 2) * D1 + c0;
        const float* w3 = W1f + (size_t)(k0 + g * 4 + 3) * D1 + c0;
#pragma unroll
        for (int c = 0; c < 16; c++) {
            acc[c] = fmaf(xv.x, w0[c], acc[c]);
            acc[c] = fmaf(xv.y, w1[c], acc[c]);
            acc[c] = fmaf(xv.z, w2[c], acc[c]);
            acc[c] = fmaf(xv.w, w3[c], acc[c]);
        }
    }
}

template <bool XF32>
DEV void gemm1_body(const void* xraw, const float* __restrict__ W1f,
                    const float* A1Sf, const float* A1Df,
                    float* h1, float* as1, float* ad1,
                    float* ldsx, int r0) {
    const int lane = threadIdx.x & 63;
    const int wid = __builtin_amdgcn_readfirstlane(threadIdx.x >> 6);
    const int c0 = wid * 16;
    float acc[16];
#pragma unroll
    for (int c = 0; c < 16; c++) acc[c] = 0.f;

    for (int tile = 0; tile < 7; tile++) {
        __syncthreads();
        stage_tile<XF32>(xraw, ldsx, r0, tile * 64, false);
        __syncthreads();
        compute_tile<16>(ldsx, W1f, tile * 64, c0, lane, acc);
    }
    __syncthreads();
    stage_tile<XF32>(xraw, ldsx, r0, 448, true);
    __syncthreads();
    compute_tile<13>(ldsx, W1f, 448, c0, lane, acc);   // 448 + 52 = 500

    const int row = r0 + lane;
    if (row >= N_NODES) return;
#pragma unroll
    for (int j = 0; j < 4; j++) {
        float4 v = make_float4(acc[4 * j], acc[4 * j + 1], acc[4 * j + 2], acc[4 * j + 3]);
        *(float4*)(h1 + (size_t)row * D1 + c0 + 4 * j) = v;
    }
#pragma unroll
    for (int hh = 0; hh < 2; hh++) {
        int h = 2 * wid + hh;
        float ts = 0.f, td = 0.f;
#pragma unroll
        for (int d = 0; d < 8; d++) {
            ts = fmaf(acc[8 * hh + d], A1Sf[h * 8 + d], ts);
            td = fmaf(acc[8 * hh + d], A1Df[h * 8 + d], td);
        }
        as1[row * HEADS + h] = ts;
        ad1[row * HEADS + h] = td;
    }
}

__global__ __launch_bounds__(256) void k_gemm1(const void* xraw, const int* flags,
                                               const float* W1f, const float* A1Sf,
                                               const float* A1Df, float* h1,
                                               float* as1, float* ad1) {
    __shared__ float ldsx[64 * LDSP];
    int r0 = blockIdx.x * 64;
    if (flags[0])
        gemm1_body<true>(xraw, W1f, A1Sf, A1Df, h1, as1, ad1, ldsx, r0);
    else
        gemm1_body<false>(xraw, W1f, A1Sf, A1Df, h1, as1, ad1, ldsx, r0);
}

// ---------------------------------------------------------------- layer-1 aggregation + ELU
// single fused edge sweep: acc = sum w*h, dsum = sum w; out = acc/dsum.
__global__ __launch_bounds__(256) void k_agg1(const int* __restrict__ csr,
                                              const int* __restrict__ off,
                                              const float* __restrict__ h1,
                                              const float* __restrict__ as1,
                                              const float* __restrict__ ad1,
                                              float* __restrict__ h1e) {
    const int lane = threadIdx.x & 63;
    const int n = (blockIdx.x * blockDim.x + threadIdx.x) >> 6;
    if (n >= N_NODES) return;
    const int beg = off[n], end = off[n + 1];
    const int h0 = lane >> 3;
    const float ad = ad1[n * HEADS + h0];
    float acc = 0.f, dsum = 0.f;
    int i = beg;
    for (; i + 4 <= end; i += 4) {
        int s0 = csr[i], s1 = csr[i + 1], s2 = csr[i + 2], s3 = csr[i + 3];
        float a0 = as1[s0 * HEADS + h0], a1 = as1[s1 * HEADS + h0];
        float a2 = as1[s2 * HEADS + h0], a3 = as1[s3 * HEADS + h0];
        float g0 = h1[(size_t)s0 * D1 + lane], g1 = h1[(size_t)s1 * D1 + lane];
        float g2 = h1[(size_t)s2 * D1 + lane], g3 = h1[(size_t)s3 * D1 + lane];
        float w0 = __expf(leaky(a0 + ad)), w1 = __expf(leaky(a1 + ad));
        float w2 = __expf(leaky(a2 + ad)), w3 = __expf(leaky(a3 + ad));
        acc = fmaf(w0, g0, acc); dsum += w0;
        acc = fmaf(w1, g1, acc); dsum += w1;
        acc = fmaf(w2, g2, acc); dsum += w2;
        acc = fmaf(w3, g3, acc); dsum += w3;
    }
    for (; i < end; i++) {
        int s = csr[i];
        float w = __expf(leaky(as1[s * HEADS + h0] + ad));
        acc = fmaf(w, h1[(size_t)s * D1 + lane], acc);
        dsum += w;
    }
    float v = acc / (dsum + 1e-16f);
    float o = v > 0.f ? v : (__expf(v) - 1.f);   // ELU
    h1e[(size_t)n * D1 + lane] = o;
}

// ---------------------------------------------------------------- GEMM2 (thread=row)
__global__ __launch_bounds__(256) void k_gemm2(const float* __restrict__ h1e,
                                               const float* __restrict__ W2f,
                                               const float* __restrict__ A2Sf,
                                               const float* __restrict__ A2Df,
                                               float* __restrict__ h2,
                                               float* __restrict__ as2,
                                               float* __restrict__ ad2) {
    const int row = blockIdx.x * blockDim.x + threadIdx.x;
    if (row >= N_NODES) return;
    float acc[NC];
#pragma unroll
    for (int c = 0; c < NC; c++) acc[c] = 0.f;
    const float* xr = h1e + (size_t)row * D1;
    for (int k = 0; k < D1; k += 4) {
        float4 hv = *(const float4*)(xr + k);
#pragma unroll
        for (int c = 0; c < NC; c++) {
            acc[c] = fmaf(hv.x, W2f[(k + 0) * NC + c], acc[c]);
            acc[c] = fmaf(hv.y, W2f[(k + 1) * NC + c], acc[c]);
            acc[c] = fmaf(hv.z, W2f[(k + 2) * NC + c], acc[c]);
            acc[c] = fmaf(hv.w, W2f[(k + 3) * NC + c], acc[c]);
        }
    }
    float ts = 0.f, td = 0.f;
#pragma unroll
    for (int c = 0; c < NC; c++) {
        h2[(size_t)row * NC + c] = acc[c];
        ts = fmaf(acc[c], A2Sf[c], ts);
        td = fmaf(acc[c], A2Df[c], td);
    }
    as2[row] = ts;
    ad2[row] = td;
}

// ---------------------------------------------------------------- layer-2 aggregation + log_softmax
__global__ __launch_bounds__(256) void k_agg2(const int* __restrict__ csr,
                                              const int* __restrict__ off,
                                              const float* __restrict__ h2,
                                              const float* __restrict__ as2,
                                              const float* __restrict__ ad2,
                                              const int* flags, void* out) {
    const int lane = threadIdx.x & 63;
    const int n = (blockIdx.x * blockDim.x + threadIdx.x) >> 6;
    if (n >= N_NODES) return;
    const int beg = off[n], end = off[n + 1];
    const float ad = ad2[n];
    const bool act = lane < NC;
    float acc = 0.f, dsum = 0.f;
    int i = beg;
    for (; i + 4 <= end; i += 4) {
        int s0 = csr[i], s1 = csr[i + 1], s2 = csr[i + 2], s3 = csr[i + 3];
        float a0 = as2[s0], a1 = as2[s1], a2 = as2[s2], a3 = as2[s3];
        float g0 = 0.f, g1 = 0.f, g2 = 0.f, g3 = 0.f;
        if (act) {
            g0 = h2[(size_t)s0 * NC + lane];
            g1 = h2[(size_t)s1 * NC + lane];
            g2 = h2[(size_t)s2 * NC + lane];
            g3 = h2[(size_t)s3 * NC + lane];
        }
        float w0 = __expf(leaky(a0 + ad)), w1 = __expf(leaky(a1 + ad));
        float w2 = __expf(leaky(a2 + ad)), w3 = __expf(leaky(a3 + ad));
        acc = fmaf(w0, g0, acc); dsum += w0;
        acc = fmaf(w1, g1, acc); dsum += w1;
        acc = fmaf(w2, g2, acc); dsum += w2;
        acc = fmaf(w3, g3, acc); dsum += w3;
    }
    for (; i < end; i++) {
        int s = csr[i];
        float w = __expf(leaky(as2[s] + ad));
        if (act) acc = fmaf(w, h2[(size_t)s * NC + lane], acc);
        dsum += w;
    }
    float val = acc / (dsum + 1e-16f);
    // log_softmax over the 41 classes
    float v = act ? val : -INFINITY;
    float m = v;
#pragma unroll
    for (int o = 1; o < 64; o <<= 1) m = fmaxf(m, __shfl_xor(m, o, 64));
    float ex = act ? __expf(val - m) : 0.f;
#pragma unroll
    for (int o = 1; o < 64; o <<= 1) ex += __shfl_xor(ex, o, 64);
    float res = val - m - __logf(ex);
    if (act) {
        if (flags[0])
            ((float*)out)[(size_t)n * NC + lane] = res;
        else
            ((__hip_bfloat16*)out)[(size_t)n * NC + lane] = __float2bfloat16(res);
    }
}

// ---------------------------------------------------------------- host
extern "C" void kernel_launch(void* const* d_in, const int* in_sizes, int n_in,
                              void* d_out, int out_size, void* d_ws, size_t ws_size,
                              hipStream_t stream) {
    char* p = (char*)d_ws;
    auto alloc = [&](size_t bytes) -> void* {
        void* r = (void*)p;
        p += (bytes + 255) & ~(size_t)255;
        return r;
    };
    int* flags  = (int*)alloc(16);
    float* W1f  = (float*)alloc((size_t)F_IN * D1 * 4);
    float* A1Sf = (float*)alloc(HEADS * HID * 4);
    float* A1Df = (float*)alloc(HEADS * HID * 4);
    float* W2f  = (float*)alloc((size_t)D1 * NC * 4);
    float* A2Sf = (float*)alloc(NC * 4);
    float* A2Df = (float*)alloc(NC * 4);
    float* h1   = (float*)alloc((size_t)N_NODES * D1 * 4);
    float* as1  = (float*)alloc((size_t)N_NODES * HEADS * 4);
    float* ad1  = (float*)alloc((size_t)N_NODES * HEADS * 4);
    float* h1e  = (float*)alloc((size_t)N_NODES * D1 * 4);
    float* h2   = (float*)alloc((size_t)N_NODES * NC * 4);
    float* as2  = (float*)alloc((size_t)N_NODES * 4);
    float* ad2  = (float*)alloc((size_t)N_NODES * 4);
    int* off    = (int*)alloc((size_t)(N_NODES + 1) * 4);
    int* csr    = (int*)alloc((size_t)N_EDGES * 4);
    int* bucket_cnt = (int*)alloc((size_t)NB * 4);
    int* cbase      = (int*)alloc((size_t)(NB + 1) * 4);
    // staging aliases h1e (dead before agg1 writes h1e): 16.06 MB <= 25.6 MB
    unsigned int* staging = (unsigned int*)h1e;

    hipMemsetAsync(bucket_cnt, 0, (size_t)NB * 4, stream);

    k_detect_convert<<<1, 256, 0, stream>>>(d_in[0], d_in[1], d_in[2], d_in[3],
                                            d_in[4], d_in[5], d_in[6], d_in[7],
                                            W1f, A1Sf, A1Df, W2f, A2Sf, A2Df, flags);
    k_bucket_scatter<<<(N_EDGES + SCHUNK - 1) / SCHUNK, 256, 0, stream>>>(d_in[1], flags, bucket_cnt, staging);
    k_cscan<<<1, 256, 0, stream>>>(bucket_cnt, cbase, off);
    k_csr_build<<<NB, 512, 0, stream>>>(staging, bucket_cnt, cbase, off, csr);

    k_gemm1<<<1563, 256, 0, stream>>>(d_in[0], flags, W1f, A1Sf, A1Df, h1, as1, ad1);
    k_agg1<<<25000, 256, 0, stream>>>(csr, off, h1, as1, ad1, h1e);
    k_gemm2<<<391, 256, 0, stream>>>(h1e, W2f, A2Sf, A2Df, h2, as2, ad2);
    k_agg2<<<25000, 256, 0, stream>>>(csr, off, h2, as2, ad2, flags, d_out);
}

// Round 4
// 758.087 us; speedup vs baseline: 3.1538x; 1.0871x over previous
//
#include <hip/hip_runtime.h>
#include <hip/hip_bf16.h>
#include <math.h>

// GAT 2-layer inference on MI355X.
// R1: gemm1 lane=row + LDS tile (broadcast-load fix).
// R2: bucketed CSR build (write-amp fix); fused single-sweep agg; gemm2 thread=row.
// R3: gemm1 -> MFMA bf16 (was VALU-bound, 41us FMA floor vs 156us actual);
//     h1/h2 gather tables stored bf16 (halves agg1/agg2 edge traffic).

#define DEV __device__ __forceinline__

constexpr int N_NODES = 100000;
constexpr int N_EDGES = 3200000;
constexpr int F_IN    = 500;
constexpr int HEADS   = 8;
constexpr int HID     = 8;
constexpr int D1      = HEADS * HID;   // 64
constexpr int NC      = 41;

// bucketed CSR build
constexpr int NB    = 196;     // buckets of 512 nodes (dst >> 9)
constexpr int BCAP  = 20480;   // staging capacity per bucket (avg 16327)
constexpr int SEPT  = 16;      // edges per thread in bucket_scatter
constexpr int SCHUNK = 256 * SEPT;   // 4096 edges per block

// gemm1 MFMA tile
constexpr int KPAD  = 512;     // K padded to 16 x 32
constexpr int LROW  = 520;     // LDS row stride in bf16 (1040B: 16B-chunk class +1 mod 8 -> 2-way only)

typedef __attribute__((ext_vector_type(8))) short bf16x8;
typedef __attribute__((ext_vector_type(4))) float f32x4;

DEV float bf2f(unsigned short u) {
    return __uint_as_float(((unsigned int)u) << 16);
}
DEV unsigned short f2b(float f) {   // RNE f32 -> bf16 bits
    unsigned int u = __float_as_uint(f);
    unsigned int r = (u + 0x7FFFu + ((u >> 16) & 1u)) >> 16;
    return (unsigned short)r;
}
DEV float leaky(float e) { return e > 0.f ? e : 0.2f * e; }

// ---------------------------------------------------------------- detect + convert weights
// Also builds W1frag: per-wave B-fragment-ordered bf16 W1 so each lane's 8
// k-values for mfma_16x16x32 are one coalesced 16B load.
// idx = wid*8192 + kb*512 + lane*8 + j  ->  W1[k = kb*32+(lane>>4)*8+j][n = wid*16+(lane&15)]
__global__ void k_detect_convert(const void* xraw, const void* eraw,
                                 const void* w1, const void* a1s, const void* a1d,
                                 const void* w2, const void* a2s, const void* a2d,
                                 unsigned short* W1frag, float* A1Sf, float* A1Df,
                                 float* W2f, float* A2Sf, float* A2Df,
                                 int* flags) {
    __shared__ int sf;
    if (threadIdx.x == 0) {
        const unsigned short* xu = (const unsigned short*)xraw;
        int valid = 0;
        for (int i = 0; i < 64; i++) {
            unsigned short v = xu[2 * i];
            int e = (v >> 7) & 0xFF;
            if (e == 0 || (e >= 90 && e <= 150)) valid++;
        }
        int xf32 = (valid < 56) ? 1 : 0;
        const unsigned int* eu = (const unsigned int*)eraw;
        int zeros = 0;
        for (int k = 0; k < 64; k++)
            if (eu[2 * k + 1] == 0u) zeros++;
        int e64 = (zeros == 64) ? 1 : 0;
        flags[0] = xf32;
        flags[1] = e64;
        sf = xf32;
    }
    __syncthreads();
    bool f32 = (sf != 0);
    auto conv = [&](const void* src, float* dst, int n) {
        if (f32) {
            const float* s = (const float*)src;
            for (int i = threadIdx.x; i < n; i += blockDim.x) dst[i] = s[i];
        } else {
            const unsigned short* s = (const unsigned short*)src;
            for (int i = threadIdx.x; i < n; i += blockDim.x) dst[i] = bf2f(s[i]);
        }
    };
    conv(a1s, A1Sf, HEADS * HID);
    conv(a1d, A1Df, HEADS * HID);
    conv(w2, W2f, D1 * NC);
    conv(a2s, A2Sf, NC);
    conv(a2d, A2Df, NC);
    for (int idx = threadIdx.x; idx < 4 * 16 * 64 * 8; idx += blockDim.x) {
        int wid = idx >> 13, kb = (idx >> 9) & 15, ln = (idx >> 3) & 63, j = idx & 7;
        int k = kb * 32 + (ln >> 4) * 8 + j;
        int n = wid * 16 + (ln & 15);
        unsigned short bits = 0;
        if (k < F_IN) {
            if (f32) bits = f2b(((const float*)w1)[k * D1 + n]);
            else     bits = ((const unsigned short*)w1)[k * D1 + n];
        }
        W1frag[idx] = bits;
    }
}

// ---------------------------------------------------------------- CSR build, pass 1
__global__ __launch_bounds__(256) void k_bucket_scatter(const void* eraw, const int* flags,
                                                        int* bucket_cnt, unsigned int* staging) {
    __shared__ int bh[NB];
    const int t = threadIdx.x;
    for (int i = t; i < NB; i += 256) bh[i] = 0;
    __syncthreads();
    const bool e64 = flags[1] != 0;
    const unsigned int* eu = (const unsigned int*)eraw;
    const int e0 = blockIdx.x * SCHUNK;
    int sv[SEPT], dv[SEPT];
#pragma unroll
    for (int k = 0; k < SEPT; k++) {
        int i = e0 + k * 256 + t;
        if (i < N_EDGES) {
            if (e64) { sv[k] = (int)eu[2 * i]; dv[k] = (int)eu[2 * (N_EDGES + i)]; }
            else     { sv[k] = (int)eu[i];     dv[k] = (int)eu[N_EDGES + i]; }
            atomicAdd(&bh[dv[k] >> 9], 1);
        } else dv[k] = -1;
    }
    __syncthreads();
    for (int i = t; i < NB; i += 256) {
        int c = bh[i];
        int base = c ? atomicAdd(&bucket_cnt[i], c) : 0;
        bh[i] = i * BCAP + base;
    }
    __syncthreads();
#pragma unroll
    for (int k = 0; k < SEPT; k++) {
        if (dv[k] >= 0) {
            int b = dv[k] >> 9;
            int slot = atomicAdd(&bh[b], 1);
            staging[slot] = (unsigned)sv[k] | ((unsigned)(dv[k] & 511) << 17);
        }
    }
}

// pass 2: scan bucket counts -> CSR bucket bases
__global__ void k_cscan(const int* bucket_cnt, int* cbase, int* off) {
    __shared__ int s[256];
    int t = threadIdx.x;
    s[t] = (t < NB) ? bucket_cnt[t] : 0;
    __syncthreads();
    for (int o = 1; o < 256; o <<= 1) {
        int v = (t >= o) ? s[t - o] : 0;
        __syncthreads();
        s[t] += v;
        __syncthreads();
    }
    if (t < NB) cbase[t + 1] = s[t];
    if (t == 0) { cbase[0] = 0; off[N_NODES] = N_EDGES; }
}

// pass 3: per-bucket LDS counters; csr writes confined to ~65KB region
__global__ __launch_bounds__(512) void k_csr_build(const unsigned int* __restrict__ staging,
                                                   const int* __restrict__ bucket_cnt,
                                                   const int* __restrict__ cbase,
                                                   int* __restrict__ off, int* __restrict__ csr) {
    __shared__ int sdeg[512];
    __shared__ int scur[512];
    const int t = threadIdx.x;
    const int b = blockIdx.x;
    const int n0 = b << 9;
    const int start = b * BCAP;
    const int end = start + bucket_cnt[b];
    const int base = cbase[b];
    sdeg[t] = 0;
    __syncthreads();
    for (int i = start + t; i < end; i += 512)
        atomicAdd(&sdeg[staging[i] >> 17], 1);
    __syncthreads();
    int d = sdeg[t];
    for (int o = 1; o < 512; o <<= 1) {
        int v = (t >= o) ? sdeg[t - o] : 0;
        __syncthreads();
        sdeg[t] += v;
        __syncthreads();
    }
    int excl = sdeg[t] - d;
    if (n0 + t < N_NODES) off[n0 + t] = base + excl;
    scur[t] = base + excl;
    __syncthreads();
    for (int i = start + t; i < end; i += 512) {
        unsigned v = staging[i];
        int slot = atomicAdd(&scur[v >> 17], 1);
        csr[slot] = (int)(v & 0x1FFFFu);
    }
}

// ---------------------------------------------------------------- GEMM1: MFMA bf16
// Block 256 thr = 4 waves; 64 rows x 64 cols; K=500 padded to 512 in LDS.
// Wave w: cols [16w,16w+16) = heads 2w,2w+1; 4 M-blocks of 16x16x32 MFMA.
// A frag: lane(m=l&15,q=l>>4) reads 8 bf16 at LDS row (mb*16+m), k=kb*32+q*8.
// B frag: one coalesced 16B load per kb from W1frag. C: col=l&15,row=q*4+reg.
__global__ __launch_bounds__(256) void k_gemm1(const void* xraw, const int* flags,
                                               const unsigned short* __restrict__ W1frag,
                                               const float* A1Sf, const float* A1Df,
                                               unsigned short* __restrict__ h1b,
                                               float* __restrict__ as1,
                                               float* __restrict__ ad1) {
    __shared__ unsigned short ldsx[64 * LROW];
    const int t = threadIdx.x;
    const int r0 = blockIdx.x * 64;
    const bool xf32 = flags[0] != 0;
    // stage: 64 rows x 128 ushort4-slots; k>=500 zero-padded
#pragma unroll
    for (int it = 0; it < 32; it++) {
        int s = it * 256 + t;
        int row = s >> 7, c4 = s & 127;
        int row_g = r0 + row;
        ushort4 v = make_ushort4(0, 0, 0, 0);
        if (c4 < 125 && row_g < N_NODES) {
            if (xf32) {
                float4 f = *(const float4*)((const float*)xraw + (size_t)row_g * F_IN + c4 * 4);
                v = make_ushort4(f2b(f.x), f2b(f.y), f2b(f.z), f2b(f.w));
            } else {
                v = *(const ushort4*)((const unsigned short*)xraw + (size_t)row_g * F_IN + c4 * 4);
            }
        }
        *(ushort4*)(ldsx + row * LROW + c4 * 4) = v;
    }
    __syncthreads();

    const int lane = t & 63;
    const int wid = __builtin_amdgcn_readfirstlane(t >> 6);
    const int m = lane & 15, q = lane >> 4;
    f32x4 acc[4] = {{0.f, 0.f, 0.f, 0.f}, {0.f, 0.f, 0.f, 0.f},
                    {0.f, 0.f, 0.f, 0.f}, {0.f, 0.f, 0.f, 0.f}};
    const unsigned short* wf = W1frag + (size_t)wid * 8192;
#pragma unroll 4
    for (int kb = 0; kb < 16; kb++) {
        bf16x8 b = *(const bf16x8*)(wf + (kb * 64 + lane) * 8);
#pragma unroll
        for (int mb = 0; mb < 4; mb++) {
            bf16x8 a = *(const bf16x8*)(ldsx + (mb * 16 + m) * LROW + kb * 32 + q * 8);
            acc[mb] = __builtin_amdgcn_mfma_f32_16x16x32_bf16(a, b, acc[mb], 0, 0, 0);
        }
    }
    // epilogue: h1b bf16 + alpha halves (f32)
    const int col = wid * 16 + m;
    const float a_s = A1Sf[col], a_d = A1Df[col];
    const int h = 2 * wid + (m >> 3);
#pragma unroll
    for (int mb = 0; mb < 4; mb++) {
#pragma unroll
        for (int reg = 0; reg < 4; reg++) {
            int gr = r0 + mb * 16 + q * 4 + reg;
            float vacc = acc[mb][reg];
            bool ok = gr < N_NODES;
            if (ok) h1b[(size_t)gr * D1 + col] = f2b(vacc);
            float ts = vacc * a_s, td = vacc * a_d;
            ts += __shfl_xor(ts, 1, 64); td += __shfl_xor(td, 1, 64);
            ts += __shfl_xor(ts, 2, 64); td += __shfl_xor(td, 2, 64);
            ts += __shfl_xor(ts, 4, 64); td += __shfl_xor(td, 4, 64);
            if (ok && (lane & 7) == 0) {
                as1[gr * HEADS + h] = ts;
                ad1[gr * HEADS + h] = td;
            }
        }
    }
}

// ---------------------------------------------------------------- layer-1 aggregation + ELU
__global__ __launch_bounds__(256) void k_agg1(const int* __restrict__ csr,
                                              const int* __restrict__ off,
                                              const unsigned short* __restrict__ h1b,
                                              const float* __restrict__ as1,
                                              const float* __restrict__ ad1,
                                              float* __restrict__ h1e) {
    const int lane = threadIdx.x & 63;
    const int n = (blockIdx.x * blockDim.x + threadIdx.x) >> 6;
    if (n >= N_NODES) return;
    const int beg = off[n], end = off[n + 1];
    const int h0 = lane >> 3;
    const float ad = ad1[n * HEADS + h0];
    float acc = 0.f, dsum = 0.f;
    int i = beg;
    for (; i + 4 <= end; i += 4) {
        int s0 = csr[i], s1 = csr[i + 1], s2 = csr[i + 2], s3 = csr[i + 3];
        float a0 = as1[s0 * HEADS + h0], a1 = as1[s1 * HEADS + h0];
        float a2 = as1[s2 * HEADS + h0], a3 = as1[s3 * HEADS + h0];
        float g0 = bf2f(h1b[(size_t)s0 * D1 + lane]), g1 = bf2f(h1b[(size_t)s1 * D1 + lane]);
        float g2 = bf2f(h1b[(size_t)s2 * D1 + lane]), g3 = bf2f(h1b[(size_t)s3 * D1 + lane]);
        float w0 = __expf(leaky(a0 + ad)), w1 = __expf(leaky(a1 + ad));
        float w2 = __expf(leaky(a2 + ad)), w3 = __expf(leaky(a3 + ad));
        acc = fmaf(w0, g0, acc); dsum += w0;
        acc = fmaf(w1, g1, acc); dsum += w1;
        acc = fmaf(w2, g2, acc); dsum += w2;
        acc = fmaf(w3, g3, acc); dsum += w3;
    }
    for (; i < end; i++) {
        int s = csr[i];
        float w = __expf(leaky(as1[s * HEADS + h0] + ad));
        acc = fmaf(w, bf2f(h1b[(size_t)s * D1 + lane]), acc);
        dsum += w;
    }
    float v = acc / (dsum + 1e-16f);
    float o = v > 0.f ? v : (__expf(v) - 1.f);   // ELU
    h1e[(size_t)n * D1 + lane] = o;
}

// ---------------------------------------------------------------- GEMM2 (thread=row)
__global__ __launch_bounds__(256) void k_gemm2(const float* __restrict__ h1e,
                                               const float* __restrict__ W2f,
                                               const float* __restrict__ A2Sf,
                                               const float* __restrict__ A2Df,
                                               unsigned short* __restrict__ h2b,
                                               float* __restrict__ as2,
                                               float* __restrict__ ad2) {
    const int row = blockIdx.x * blockDim.x + threadIdx.x;
    if (row >= N_NODES) return;
    float acc[NC];
#pragma unroll
    for (int c = 0; c < NC; c++) acc[c] = 0.f;
    const float* xr = h1e + (size_t)row * D1;
    for (int k = 0; k < D1; k += 4) {
        float4 hv = *(const float4*)(xr + k);
#pragma unroll
        for (int c = 0; c < NC; c++) {
            acc[c] = fmaf(hv.x, W2f[(k + 0) * NC + c], acc[c]);
            acc[c] = fmaf(hv.y, W2f[(k + 1) * NC + c], acc[c]);
            acc[c] = fmaf(hv.z, W2f[(k + 2) * NC + c], acc[c]);
            acc[c] = fmaf(hv.w, W2f[(k + 3) * NC + c], acc[c]);
        }
    }
    float ts = 0.f, td = 0.f;
#pragma unroll
    for (int c = 0; c < NC; c++) {
        h2b[(size_t)row * NC + c] = f2b(acc[c]);
        ts = fmaf(acc[c], A2Sf[c], ts);
        td = fmaf(acc[c], A2Df[c], td);
    }
    as2[row] = ts;
    ad2[row] = td;
}

// ---------------------------------------------------------------- layer-2 aggregation + log_softmax
__global__ __launch_bounds__(256) void k_agg2(const int* __restrict__ csr,
                                              const int* __restrict__ off,
                                              const unsigned short* __restrict__ h2b,
                                              const float* __restrict__ as2,
                                              const float* __restrict__ ad2,
                                              const int* flags, void* out) {
    const int lane = threadIdx.x & 63;
    const int n = (blockIdx.x * blockDim.x + threadIdx.x) >> 6;
    if (n >= N_NODES) return;
    const int beg = off[n], end = off[n + 1];
    const float ad = ad2[n];
    const bool act = lane < NC;
    const int cl = act ? lane : 0;
    float acc = 0.f, dsum = 0.f;
    int i = beg;
    for (; i + 4 <= end; i += 4) {
        int s0 = csr[i], s1 = csr[i + 1], s2 = csr[i + 2], s3 = csr[i + 3];
        float a0 = as2[s0], a1 = as2[s1], a2 = as2[s2], a3 = as2[s3];
        float g0 = bf2f(h2b[(size_t)s0 * NC + cl]);
        float g1 = bf2f(h2b[(size_t)s1 * NC + cl]);
        float g2 = bf2f(h2b[(size_t)s2 * NC + cl]);
        float g3 = bf2f(h2b[(size_t)s3 * NC + cl]);
        float w0 = __expf(leaky(a0 + ad)), w1 = __expf(leaky(a1 + ad));
        float w2 = __expf(leaky(a2 + ad)), w3 = __expf(leaky(a3 + ad));
        acc = fmaf(w0, g0, acc); dsum += w0;
        acc = fmaf(w1, g1, acc); dsum += w1;
        acc = fmaf(w2, g2, acc); dsum += w2;
        acc = fmaf(w3, g3, acc); dsum += w3;
    }
    for (; i < end; i++) {
        int s = csr[i];
        float w = __expf(leaky(as2[s] + ad));
        acc = fmaf(w, bf2f(h2b[(size_t)s * NC + cl]), acc);
        dsum += w;
    }
    float val = acc / (dsum + 1e-16f);
    float v = act ? val : -INFINITY;
    float m = v;
#pragma unroll
    for (int o = 1; o < 64; o <<= 1) m = fmaxf(m, __shfl_xor(m, o, 64));
    float ex = act ? __expf(val - m) : 0.f;
#pragma unroll
    for (int o = 1; o < 64; o <<= 1) ex += __shfl_xor(ex, o, 64);
    float res = val - m - __logf(ex);
    if (act) {
        if (flags[0])
            ((float*)out)[(size_t)n * NC + lane] = res;
        else
            ((__hip_bfloat16*)out)[(size_t)n * NC + lane] = __float2bfloat16(res);
    }
}

// ---------------------------------------------------------------- host
extern "C" void kernel_launch(void* const* d_in, const int* in_sizes, int n_in,
                              void* d_out, int out_size, void* d_ws, size_t ws_size,
                              hipStream_t stream) {
    char* p = (char*)d_ws;
    auto alloc = [&](size_t bytes) -> void* {
        void* r = (void*)p;
        p += (bytes + 255) & ~(size_t)255;
        return r;
    };
    int* flags  = (int*)alloc(16);
    unsigned short* W1frag = (unsigned short*)alloc(4 * 16 * 64 * 8 * 2);
    float* A1Sf = (float*)alloc(HEADS * HID * 4);
    float* A1Df = (float*)alloc(HEADS * HID * 4);
    float* W2f  = (float*)alloc((size_t)D1 * NC * 4);
    float* A2Sf = (float*)alloc(NC * 4);
    float* A2Df = (float*)alloc(NC * 4);
    unsigned short* h1b = (unsigned short*)alloc((size_t)N_NODES * D1 * 2);
    float* as1  = (float*)alloc((size_t)N_NODES * HEADS * 4);
    float* ad1  = (float*)alloc((size_t)N_NODES * HEADS * 4);
    float* h1e  = (float*)alloc((size_t)N_NODES * D1 * 4);
    unsigned short* h2b = (unsigned short*)alloc((size_t)N_NODES * NC * 2);
    float* as2  = (float*)alloc((size_t)N_NODES * 4);
    float* ad2  = (float*)alloc((size_t)N_NODES * 4);
    int* off    = (int*)alloc((size_t)(N_NODES + 1) * 4);
    int* csr    = (int*)alloc((size_t)N_EDGES * 4);
    int* bucket_cnt = (int*)alloc((size_t)NB * 4);
    int* cbase      = (int*)alloc((size_t)(NB + 1) * 4);
    // staging aliases h1e (dead until agg1 writes h1e): 16.06 MB <= 25.6 MB
    unsigned int* staging = (unsigned int*)h1e;

    hipMemsetAsync(bucket_cnt, 0, (size_t)NB * 4, stream);

    k_detect_convert<<<1, 256, 0, stream>>>(d_in[0], d_in[1], d_in[2], d_in[3],
                                            d_in[4], d_in[5], d_in[6], d_in[7],
                                            W1frag, A1Sf, A1Df, W2f, A2Sf, A2Df, flags);
    k_bucket_scatter<<<(N_EDGES + SCHUNK - 1) / SCHUNK, 256, 0, stream>>>(d_in[1], flags, bucket_cnt, staging);
    k_cscan<<<1, 256, 0, stream>>>(bucket_cnt, cbase, off);
    k_csr_build<<<NB, 512, 0, stream>>>(staging, bucket_cnt, cbase, off, csr);

    k_gemm1<<<1563, 256, 0, stream>>>(d_in[0], flags, W1frag, A1Sf, A1Df, h1b, as1, ad1);
    k_agg1<<<25000, 256, 0, stream>>>(csr, off, h1b, as1, ad1, h1e);
    k_gemm2<<<391, 256, 0, stream>>>(h1e, W2f, A2Sf, A2Df, h2b, as2, ad2);
    k_agg2<<<25000, 256, 0, stream>>>(csr, off, h2b, as2, ad2, flags, d_out);
}